// Round 6
// baseline (421.825 us; speedup 1.0000x reference)
//
#include <hip/hip_runtime.h>
#include <math.h>

// Problem constants
#define BB 4
#define LL 1024
#define DD 512
#define HH 8
#define DHH 64
#define EE 65536
#define NNODES 4096
#define HD 512
#define TWO_D 1024

typedef short bf16x8 __attribute__((ext_vector_type(8)));
typedef short short4v __attribute__((ext_vector_type(4)));
typedef float f32x4 __attribute__((ext_vector_type(4)));
typedef unsigned int u32;
#define GL_AS __attribute__((address_space(1)))
#define LDS_AS __attribute__((address_space(3)))

__device__ __forceinline__ short f2bf(float f) {   // RNE fp32->bf16
  u32 u = __builtin_bit_cast(u32, f);
  u = (u + 0x7fffu + ((u >> 16) & 1u)) >> 16;
  return (short)u;
}
__device__ __forceinline__ float b2f(short s) {
  u32 u = ((u32)(unsigned short)s) << 16;
  return __builtin_bit_cast(float, u);
}
__device__ __forceinline__ void gload_lds16(const short* g, short* l) {
  __builtin_amdgcn_global_load_lds((GL_AS const u32*)g, (LDS_AS u32*)l, 16, 0, 0);
}

// ---- stage ROWS x 32 bf16 tile (linear LDS, used by plain GEMMs)
template <int ROWS>
__device__ __forceinline__ void stage32(const short* g, int lda, short* lds, int tid) {
  const int w = tid >> 6, l = tid & 63;
#pragma unroll
  for (int rep = 0; rep < ROWS / 64; ++rep) {
    const int rbase = rep * 64 + w * 16;
    gload_lds16(g + (size_t)(rbase + (l >> 2)) * lda + (l & 3) * 8, lds + rbase * 32);
  }
}

// ---- one K=32 MFMA step from linear LDS tiles (BT layout both sides)
template <int MREP, int NREP>
__device__ __forceinline__ void mfma_step(const short* As, const short* Bs, int lds_ld, int kofs,
                                          f32x4 (&acc)[MREP][NREP], int wr, int wc, int l) {
  bf16x8 a[MREP], b[NREP];
#pragma unroll
  for (int mi = 0; mi < MREP; ++mi) {
    const int row = wr * (MREP * 16) + mi * 16 + (l & 15);
    a[mi] = *(const bf16x8*)(As + row * lds_ld + kofs + ((l >> 4) << 3));
  }
#pragma unroll
  for (int ni = 0; ni < NREP; ++ni) {
    const int row = wc * (NREP * 16) + ni * 16 + (l & 15);
    b[ni] = *(const bf16x8*)(Bs + row * lds_ld + kofs + ((l >> 4) << 3));
  }
#pragma unroll
  for (int mi = 0; mi < MREP; ++mi)
#pragma unroll
    for (int ni = 0; ni < NREP; ++ni)
      acc[mi][ni] = __builtin_amdgcn_mfma_f32_16x16x32_bf16(a[mi], b[ni], acc[mi][ni], 0, 0, 0);
}

// ---- swizzled LDS read: row-major tile, ROWB bytes per row, XOR bank swizzle
template <int ROWB>
__device__ __forceinline__ bf16x8 ldsw(const short* base, int row, int bir) {
  const int bo = (row * ROWB + bir) ^ ((row & 7) << 4);
  return *(const bf16x8*)((const char*)base + bo);
}

// ===========================================================================
// casts
// ===========================================================================
__global__ __launch_bounds__(256) void k_cast_x(const float* __restrict__ x, short* __restrict__ xb) {
  const int i = (blockIdx.x * 256 + threadIdx.x) * 8;
  float4 f0 = *(const float4*)(x + i), f1 = *(const float4*)(x + i + 4);
  bf16x8 s;
  s[0] = f2bf(f0.x); s[1] = f2bf(f0.y); s[2] = f2bf(f0.z); s[3] = f2bf(f0.w);
  s[4] = f2bf(f1.x); s[5] = f2bf(f1.y); s[6] = f2bf(f1.z); s[7] = f2bf(f1.w);
  *(bf16x8*)(xb + i) = s;
}

// 5 x [512][512] fp32 -> bf16 transposed; grid (16,16,5), block (32,8)
__global__ __launch_bounds__(256) void k_tcast5(const float* __restrict__ Wq, const float* __restrict__ Wk,
                                                const float* __restrict__ Wv, const float* __restrict__ Wmp,
                                                const float* __restrict__ Wo,
                                                short* __restrict__ WcatT, short* __restrict__ WoT) {
  __shared__ float t[32][33];
  const int zz = blockIdx.z;
  const float* W = (zz == 0) ? Wq : (zz == 1) ? Wk : (zz == 2) ? Wv : (zz == 3) ? Wmp : Wo;
  short* out = (zz < 4) ? (WcatT + zz * 512 * 512) : WoT;
  const int k0 = blockIdx.y * 32, n0 = blockIdx.x * 32;
  const int tx = threadIdx.x, ty = threadIdx.y;
#pragma unroll
  for (int i = 0; i < 4; ++i)
    t[ty + 8 * i][tx] = W[(size_t)(k0 + ty + 8 * i) * 512 + n0 + tx];
  __syncthreads();
#pragma unroll
  for (int i = 0; i < 4; ++i)
    out[(size_t)(n0 + ty + 8 * i) * 512 + k0 + tx] = f2bf(t[tx][ty + 8 * i]);
}

// W fp32 [K][N] -> out bf16 [N][K]; grid (N/32, K/32), block (32,8)
__global__ __launch_bounds__(256) void k_tcast(const float* __restrict__ W, short* __restrict__ out,
                                               int K, int N) {
  __shared__ float t[32][33];
  const int k0 = blockIdx.y * 32, n0 = blockIdx.x * 32;
  const int tx = threadIdx.x, ty = threadIdx.y;
#pragma unroll
  for (int i = 0; i < 4; ++i)
    t[ty + 8 * i][tx] = W[(size_t)(k0 + ty + 8 * i) * N + n0 + tx];
  __syncthreads();
#pragma unroll
  for (int i = 0; i < 4; ++i)
    out[(size_t)(n0 + ty + 8 * i) * K + k0 + tx] = f2bf(t[tx][ty + 8 * i]);
}

__global__ __launch_bounds__(256) void k_pack_bias(const float* bq, const float* bk,
                                                   const float* bv, const float* bmp,
                                                   float* __restrict__ bcat) {
  const int i = blockIdx.x * 256 + threadIdx.x;
  const float* src = (i < 512) ? bq : (i < 1024) ? bk : (i < 1536) ? bv : bmp;
  bcat[i] = src[i & 511];
}

// ===========================================================================
// fused QKV + message-passing GEMM: [4096x512] @ [512x2048] (BT weights)
// ===========================================================================
__global__ __launch_bounds__(256) void k_gemm_qkvg(const short* __restrict__ A,
                                                   const short* __restrict__ Bw,
                                                   const float* __restrict__ bcat,
                                                   const float* __restrict__ x,
                                                   short* __restrict__ qT, short* __restrict__ kT,
                                                   short* __restrict__ vT, short* __restrict__ g_bf) {
  __shared__ __align__(16) short As[128 * 32];
  __shared__ __align__(16) short Bs[128 * 32];
  const int tid = threadIdx.x, l = tid & 63, w = tid >> 6, wr = w >> 1, wc = w & 1;
  const int m0 = blockIdx.y * 128, n0 = blockIdx.x * 128;
  f32x4 acc[4][4] = {};
  for (int k0 = 0; k0 < 512; k0 += 32) {
    stage32<128>(A + (size_t)m0 * 512 + k0, 512, As, tid);
    stage32<128>(Bw + (size_t)n0 * 512 + k0, 512, Bs, tid);
    __syncthreads();
    mfma_step<4, 4>(As, Bs, 32, 0, acc, wr, wc, l);
    __syncthreads();
  }
  const int lr = l >> 4, lc = l & 15;
#pragma unroll
  for (int mi = 0; mi < 4; ++mi)
#pragma unroll
    for (int ni = 0; ni < 4; ++ni) {
      const int col = n0 + wc * 64 + ni * 16 + lc;
      const int which = col >> 9;
#pragma unroll
      for (int r = 0; r < 4; ++r) {
        const int row = m0 + wr * 64 + mi * 16 + lr * 4 + r;
        float v = acc[mi][ni][r] + bcat[col];
        if (which < 3) {
          const int hh = (col >> 6) & 7, dh = col & 63;
          const int bb = row >> 10, ll2 = row & 1023;
          short* dst = (which == 0) ? qT : (which == 1) ? kT : vT;
          dst[((size_t)((bb * 8 + hh) * 1024 + ll2)) * 64 + dh] = f2bf(v);
        } else {
          const int c = col & 511;
          g_bf[(size_t)row * 512 + c] = f2bf(v + x[(size_t)row * 512 + c]);
        }
      }
    }
}

// ===========================================================================
// generic BT GEMM 64x128 tile: ex (K=1024) and out-proj (K=512)
// ===========================================================================
__global__ __launch_bounds__(256) void k_gemm_ex(const short* __restrict__ A,
                                                 const short* __restrict__ Bw,
                                                 const float* __restrict__ bias,
                                                 short* __restrict__ C) {
  __shared__ __align__(16) short As[64 * 32];
  __shared__ __align__(16) short Bs[128 * 32];
  const int tid = threadIdx.x, l = tid & 63, w = tid >> 6, wr = w >> 1, wc = w & 1;
  const int m0 = blockIdx.y * 64, n0 = blockIdx.x * 128;
  f32x4 acc[2][4] = {};
  for (int k0 = 0; k0 < 1024; k0 += 32) {
    stage32<64>(A + (size_t)m0 * 1024 + k0, 1024, As, tid);
    stage32<128>(Bw + (size_t)n0 * 1024 + k0, 1024, Bs, tid);
    __syncthreads();
    mfma_step<2, 4>(As, Bs, 32, 0, acc, wr, wc, l);
    __syncthreads();
  }
  const int lr = l >> 4, lc = l & 15;
#pragma unroll
  for (int mi = 0; mi < 2; ++mi)
#pragma unroll
    for (int ni = 0; ni < 4; ++ni) {
      const int col = n0 + wc * 64 + ni * 16 + lc;
      const float bv = bias[col];
#pragma unroll
      for (int r = 0; r < 4; ++r) {
        const int row = m0 + wr * 32 + mi * 16 + lr * 4 + r;
        C[(size_t)row * 512 + col] = f2bf(acc[mi][ni][r] + bv);
      }
    }
}

__global__ __launch_bounds__(256) void k_gemm_oproj(const short* __restrict__ A,
                                                    const short* __restrict__ Bw,
                                                    const float* __restrict__ bias,
                                                    float* __restrict__ C) {
  __shared__ __align__(16) short As[64 * 32];
  __shared__ __align__(16) short Bs[128 * 32];
  const int tid = threadIdx.x, l = tid & 63, w = tid >> 6, wr = w >> 1, wc = w & 1;
  const int m0 = blockIdx.y * 64, n0 = blockIdx.x * 128;
  f32x4 acc[2][4] = {};
  for (int k0 = 0; k0 < 512; k0 += 32) {
    stage32<64>(A + (size_t)m0 * 512 + k0, 512, As, tid);
    stage32<128>(Bw + (size_t)n0 * 512 + k0, 512, Bs, tid);
    __syncthreads();
    mfma_step<2, 4>(As, Bs, 32, 0, acc, wr, wc, l);
    __syncthreads();
  }
  const int lr = l >> 4, lc = l & 15;
#pragma unroll
  for (int mi = 0; mi < 2; ++mi)
#pragma unroll
    for (int ni = 0; ni < 4; ++ni) {
      const int col = n0 + wc * 64 + ni * 16 + lc;
      const float bv = bias[col];
#pragma unroll
      for (int r = 0; r < 4; ++r) {
        const int row = m0 + wr * 32 + mi * 16 + lr * 4 + r;
        C[(size_t)row * 512 + col] = acc[mi][ni][r] + bv;
      }
    }
}

// ===========================================================================
// K_struct combined bias: Ksc = ss * (ex@ex^T)/sqrt(512) + Bg   (causal tiles)
// ===========================================================================
__global__ __launch_bounds__(256) void k_kstruct(const short* __restrict__ ex,
                                                 const float* __restrict__ Bg,
                                                 const float* __restrict__ ssp,
                                                 float* __restrict__ Ksc) {
  const int mt = blockIdx.y, nt = blockIdx.x, b = blockIdx.z;
  if (nt > mt) return;
  __shared__ __align__(16) short As[128 * 32];
  __shared__ __align__(16) short Bs[128 * 32];
  const int tid = threadIdx.x, l = tid & 63, w = tid >> 6, wr = w >> 1, wc = w & 1;
  const int m0 = mt * 128, n0 = nt * 128;
  const short* Az = ex + (size_t)b * 1024 * 512;
  f32x4 acc[4][4] = {};
  for (int k0 = 0; k0 < 512; k0 += 32) {
    stage32<128>(Az + (size_t)m0 * 512 + k0, 512, As, tid);
    stage32<128>(Az + (size_t)n0 * 512 + k0, 512, Bs, tid);
    __syncthreads();
    mfma_step<4, 4>(As, Bs, 32, 0, acc, wr, wc, l);
    __syncthreads();
  }
  const float sc = ssp[0] * 0.04419417382415922f;  // ss / sqrt(512)
  const float* Bgb = Bg + (size_t)b * 1024 * 1024;
  float* Kb = Ksc + (size_t)b * 1024 * 1024;
  const int lr = l >> 4, lc = l & 15;
#pragma unroll
  for (int mi = 0; mi < 4; ++mi)
#pragma unroll
    for (int ni = 0; ni < 4; ++ni) {
      const int col = n0 + wc * 64 + ni * 16 + lc;
#pragma unroll
      for (int r = 0; r < 4; ++r) {
        const int row = m0 + wr * 64 + mi * 16 + lr * 4 + r;
        Kb[(size_t)row * 1024 + col] = fmaf(acc[mi][ni][r], sc, Bgb[(size_t)row * 1024 + col]);
      }
    }
}

// ===========================================================================
// Fused attention: scores + softmax + PV, two-pass flash style.
// grid (16, 32): bx -> mt (complement-remapped for balance), by -> z.
// Block: 64 Q-rows, col tiles of 128, 4 waves.
// ===========================================================================
__global__ __launch_bounds__(256) void k_attn(const short* __restrict__ qT,
                                              const short* __restrict__ kT,
                                              const short* __restrict__ vT,
                                              const float* __restrict__ Ksc,
                                              float* __restrict__ attn,
                                              short* __restrict__ o_bf) {
  __shared__ __align__(16) short Qs[64 * 64];    // [qrow][k]   swizzled
  __shared__ __align__(16) short Ks[128 * 64];   // [kcol][k]   swizzled
  __shared__ __align__(16) short Ps[64 * 128];   // [qrow][j]   swizzled
  __shared__ __align__(16) short Vls[64 * 128];  // [dh][j]     swizzled
  __shared__ float mred[2][64], sred[2][64];

  const int tid = threadIdx.x, l = tid & 63, w = tid >> 6;
  const int wr = w >> 1, wc = w & 1, lr = l >> 4, lc = l & 15;
  const int z = blockIdx.y, b = z >> 3, h = z & 7;
  const int mt = (z & 16) ? (15 - (int)blockIdx.x) : (int)blockIdx.x;
  const int r0 = mt * 64;
  const int NT = (mt + 2) >> 1;  // col tiles needed (last one contains diagonal)

  const short* Qz = qT + (size_t)z * 65536 + (size_t)r0 * 64;
  const short* Kz = kT + (size_t)z * 65536;
  const short* Vz = vT + (size_t)z * 65536;
  const float* Kb = Ksc + (size_t)b * 1048576 + (size_t)r0 * 1024;
  float* Az = attn + (size_t)z * 1048576 + (size_t)r0 * 1024;

  // stage Q (source pre-swizzled for XOR-bank layout)
#pragma unroll
  for (int rep = 0; rep < 2; ++rep) {
    const int rbase = w * 16 + rep * 8;
    gload_lds16(Qz + (size_t)(rbase + (l >> 3)) * 64 + ((l & 7) ^ (l >> 3)) * 8,
                Qs + rbase * 64);
  }

  // zero-fill attn cols >= NT*128 for our 64 rows (mandatory: d_out is poisoned)
  const int zc0 = NT * 128;
  if (zc0 < 1024) {
    const int cw = (1024 - zc0) >> 2;
    for (int idx = tid; idx < 64 * cw; idx += 256) {
      const int rowi = idx / cw, c4 = idx - rowi * cw;
      float4 zf = {0.f, 0.f, 0.f, 0.f};
      *(float4*)&Az[(size_t)rowi * 1024 + zc0 + (c4 << 2)] = zf;
    }
  }

  float m8[8], s8[8];
#pragma unroll
  for (int i = 0; i < 8; ++i) { m8[i] = -INFINITY; s8[i] = 0.f; }

  // ---------------- pass 1: per-row online max / sum ----------------
  for (int nt = 0; nt < NT; ++nt) {
    const int n0 = nt * 128;
    __syncthreads();
#pragma unroll
    for (int rep = 0; rep < 4; ++rep) {
      const int rbase = rep * 32 + w * 8;
      gload_lds16(Kz + (size_t)(n0 + rbase + (l >> 3)) * 64 + ((l & 7) ^ (l >> 3)) * 8,
                  Ks + rbase * 64);
    }
    __syncthreads();
    f32x4 acc[2][4] = {};
#pragma unroll
    for (int kk = 0; kk < 2; ++kk) {
      const int bir = kk * 64 + lr * 16;
      bf16x8 a[2], bb[4];
#pragma unroll
      for (int mi = 0; mi < 2; ++mi) a[mi] = ldsw<128>(Qs, wr * 32 + mi * 16 + lc, bir);
#pragma unroll
      for (int ni = 0; ni < 4; ++ni) bb[ni] = ldsw<128>(Ks, wc * 64 + ni * 16 + lc, bir);
#pragma unroll
      for (int mi = 0; mi < 2; ++mi)
#pragma unroll
        for (int ni = 0; ni < 4; ++ni)
          acc[mi][ni] = __builtin_amdgcn_mfma_f32_16x16x32_bf16(a[mi], bb[ni], acc[mi][ni], 0, 0, 0);
    }
    const bool lastT = (nt == NT - 1);
#pragma unroll
    for (int mi = 0; mi < 2; ++mi)
#pragma unroll
      for (int rr = 0; rr < 4; ++rr) {
        const int row = wr * 32 + mi * 16 + lr * 4 + rr;
        const int slot = mi * 4 + rr;
        float vals[4], tm = -INFINITY;
#pragma unroll
        for (int ni = 0; ni < 4; ++ni) {
          const int col = wc * 64 + ni * 16 + lc;
          float sc = fmaf(acc[mi][ni][rr], 0.125f, Kb[(size_t)row * 1024 + n0 + col]);
          if (lastT && (n0 + col > r0 + row)) sc = -INFINITY;
          vals[ni] = sc;
          tm = fmaxf(tm, sc);
        }
        if (tm > -INFINITY) {
          const float mn = fmaxf(m8[slot], tm);
          float ts = 0.f;
#pragma unroll
          for (int ni = 0; ni < 4; ++ni) ts += expf(vals[ni] - mn);
          s8[slot] = s8[slot] * expf(m8[slot] - mn) + ts;
          m8[slot] = mn;
        }
      }
  }

  // cross-lane combine (16 lanes share the same 8 rows)
#pragma unroll
  for (int off = 1; off < 16; off <<= 1)
#pragma unroll
    for (int i = 0; i < 8; ++i) {
      const float mo = __shfl_xor(m8[i], off, 64);
      const float so = __shfl_xor(s8[i], off, 64);
      const float mn = fmaxf(m8[i], mo);
      if (mn > -INFINITY)
        s8[i] = s8[i] * expf(m8[i] - mn) + so * expf(mo - mn);
      m8[i] = mn;
    }
  // cross-wave (wc halves) combine via LDS
  if (lc == 0) {
#pragma unroll
    for (int mi = 0; mi < 2; ++mi)
#pragma unroll
      for (int rr = 0; rr < 4; ++rr) {
        const int row = wr * 32 + mi * 16 + lr * 4 + rr;
        mred[wc][row] = m8[mi * 4 + rr];
        sred[wc][row] = s8[mi * 4 + rr];
      }
  }
  __syncthreads();
  float mf[8], inv_s[8];
#pragma unroll
  for (int mi = 0; mi < 2; ++mi)
#pragma unroll
    for (int rr = 0; rr < 4; ++rr) {
      const int row = wr * 32 + mi * 16 + lr * 4 + rr;
      const float ma = mred[0][row], mb = mred[1][row];
      const float mF = fmaxf(ma, mb);
      const float sF = sred[0][row] * expf(ma - mF) + sred[1][row] * expf(mb - mF);
      mf[mi * 4 + rr] = mF;
      inv_s[mi * 4 + rr] = 1.0f / sF;
    }

  // ---------------- pass 2: write P, accumulate O = P @ V ----------------
  f32x4 oacc[4];
#pragma unroll
  for (int i = 0; i < 4; ++i) oacc[i] = f32x4{0.f, 0.f, 0.f, 0.f};

  for (int nt = 0; nt < NT; ++nt) {
    const int n0 = nt * 128;
    __syncthreads();
#pragma unroll
    for (int rep = 0; rep < 4; ++rep) {
      const int rbase = rep * 32 + w * 8;
      gload_lds16(Kz + (size_t)(n0 + rbase + (l >> 3)) * 64 + ((l & 7) ^ (l >> 3)) * 8,
                  Ks + rbase * 64);
    }
    // reg-stage V tile transposed into Vls[dh][j] (swizzled writes)
    {
      const int j = tid >> 1, d0 = (tid & 1) * 32;
      const short* vsrc = Vz + (size_t)(n0 + j) * 64 + d0;
      bf16x8 v0 = *(const bf16x8*)(vsrc);
      bf16x8 v1 = *(const bf16x8*)(vsrc + 8);
      bf16x8 v2 = *(const bf16x8*)(vsrc + 16);
      bf16x8 v3 = *(const bf16x8*)(vsrc + 24);
#pragma unroll
      for (int i = 0; i < 8; ++i) {
        int dh = d0 + i;
        *(short*)((char*)Vls + ((dh * 256 + j * 2) ^ ((dh & 7) << 4))) = v0[i];
        dh = d0 + 8 + i;
        *(short*)((char*)Vls + ((dh * 256 + j * 2) ^ ((dh & 7) << 4))) = v1[i];
        dh = d0 + 16 + i;
        *(short*)((char*)Vls + ((dh * 256 + j * 2) ^ ((dh & 7) << 4))) = v2[i];
        dh = d0 + 24 + i;
        *(short*)((char*)Vls + ((dh * 256 + j * 2) ^ ((dh & 7) << 4))) = v3[i];
      }
    }
    __syncthreads();
    f32x4 acc[2][4] = {};
#pragma unroll
    for (int kk = 0; kk < 2; ++kk) {
      const int bir = kk * 64 + lr * 16;
      bf16x8 a[2], bb[4];
#pragma unroll
      for (int mi = 0; mi < 2; ++mi) a[mi] = ldsw<128>(Qs, wr * 32 + mi * 16 + lc, bir);
#pragma unroll
      for (int ni = 0; ni < 4; ++ni) bb[ni] = ldsw<128>(Ks, wc * 64 + ni * 16 + lc, bir);
#pragma unroll
      for (int mi = 0; mi < 2; ++mi)
#pragma unroll
        for (int ni = 0; ni < 4; ++ni)
          acc[mi][ni] = __builtin_amdgcn_mfma_f32_16x16x32_bf16(a[mi], bb[ni], acc[mi][ni], 0, 0, 0);
    }
    const bool lastT = (nt == NT - 1);
#pragma unroll
    for (int mi = 0; mi < 2; ++mi)
#pragma unroll
      for (int rr = 0; rr < 4; ++rr) {
        const int row = wr * 32 + mi * 16 + lr * 4 + rr;
        const int slot = mi * 4 + rr;
#pragma unroll
        for (int ni = 0; ni < 4; ++ni) {
          const int col = wc * 64 + ni * 16 + lc;
          const float sc = fmaf(acc[mi][ni][rr], 0.125f, Kb[(size_t)row * 1024 + n0 + col]);
          float p = 0.f;
          if (!(lastT && (n0 + col > r0 + row)))
            p = expf(sc - mf[slot]) * inv_s[slot];
          Az[(size_t)row * 1024 + n0 + col] = p;
          *(short*)((char*)Ps + ((row * 256 + col * 2) ^ ((row & 7) << 4))) = f2bf(p);
        }
      }
    __syncthreads();
    // PV: wave w owns O rows w*16..w*16+15, all 64 dh; K = 128 cols
#pragma unroll
    for (int ks = 0; ks < 4; ++ks) {
      const int bir = ks * 64 + lr * 16;
      bf16x8 a = ldsw<256>(Ps, w * 16 + lc, bir);
#pragma unroll
      for (int ni = 0; ni < 4; ++ni) {
        bf16x8 bb = ldsw<256>(Vls, ni * 16 + lc, bir);
        oacc[ni] = __builtin_amdgcn_mfma_f32_16x16x32_bf16(a, bb, oacc[ni], 0, 0, 0);
      }
    }
  }

  // O epilogue -> o_bf [b*1024+row][h*64+dh]
#pragma unroll
  for (int ni = 0; ni < 4; ++ni)
#pragma unroll
    for (int rr = 0; rr < 4; ++rr) {
      const int row = r0 + w * 16 + lr * 4 + rr;
      const int dh = ni * 16 + lc;
      o_bf[((size_t)(b * 1024 + row)) * 512 + h * 64 + dh] = f2bf(oacc[ni][rr]);
    }
}

// ===========================================================================
// segment mean over sorted indicator (g bf16 -> hp fp32)
// ===========================================================================
__global__ __launch_bounds__(128) void k_segmean(const short* __restrict__ g,
                                                 const int* __restrict__ idx,
                                                 const int* __restrict__ ind,
                                                 float* __restrict__ hp) {
  __shared__ int sh[2];
  const int s = blockIdx.x;
  if (threadIdx.x == 0) {
    int lo = 0, hi = EE;
    while (lo < hi) { int mid = (lo + hi) >> 1; if (ind[mid] < s) lo = mid + 1; else hi = mid; }
    sh[0] = lo;
    int lo2 = lo, hi2 = EE;
    while (lo2 < hi2) { int mid = (lo2 + hi2) >> 1; if (ind[mid] <= s) lo2 = mid + 1; else hi2 = mid; }
    sh[1] = lo2;
  }
  __syncthreads();
  const int lo = sh[0], hi = sh[1];
  const int d0 = threadIdx.x << 2;
  float a0 = 0.f, a1 = 0.f, a2 = 0.f, a3 = 0.f;
  for (int e = lo; e < hi; ++e) {
    const short4v v = *(const short4v*)(g + (size_t)idx[e] * 512 + d0);
    a0 += b2f(v[0]); a1 += b2f(v[1]); a2 += b2f(v[2]); a3 += b2f(v[3]);
  }
  const float ic = (hi > lo) ? 1.0f / (float)(hi - lo) : 0.0f;
  float4 o = {a0 * ic, a1 * ic, a2 * ic, a3 * ic};
  *(float4*)(hp + (size_t)s * 512 + d0) = o;
}

// ===========================================================================
// BN stats, row-major two-stage
// ===========================================================================
__global__ __launch_bounds__(256) void k_stats1(const float* __restrict__ x,
                                                const float* __restrict__ hp,
                                                float* __restrict__ scr) {
  const int blk = blockIdx.x, tid = threadIdx.x;
  const int c = tid * 2, r0 = blk * 128;
  float sx0 = 0, sx1 = 0, qx0 = 0, qx1 = 0, sh0 = 0, sh1 = 0, qh0 = 0, qh1 = 0;
  for (int r = 0; r < 128; ++r) {
    const size_t off = (size_t)(r0 + r) * 512 + c;
    float2 vx = *(const float2*)(x + off);
    float2 vh = *(const float2*)(hp + off);
    sx0 += vx.x; sx1 += vx.y; qx0 = fmaf(vx.x, vx.x, qx0); qx1 = fmaf(vx.y, vx.y, qx1);
    sh0 += vh.x; sh1 += vh.y; qh0 = fmaf(vh.x, vh.x, qh0); qh1 = fmaf(vh.y, vh.y, qh1);
  }
  float* p = scr + (size_t)blk * 4096;
  p[c] = sx0; p[c + 1] = sx1;
  p[512 + c] = sh0; p[512 + c + 1] = sh1;
  p[2048 + c] = qx0; p[2048 + c + 1] = qx1;
  p[2048 + 512 + c] = qh0; p[2048 + 512 + c + 1] = qh1;
}
__global__ __launch_bounds__(128) void k_stats2(const float* __restrict__ scr,
                                                float* __restrict__ mu, float* __restrict__ inv) {
  const int f = blockIdx.x * 128 + threadIdx.x;
  float s = 0.f, q = 0.f;
  for (int i = 0; i < 32; ++i) {
    s += scr[(size_t)i * 4096 + f];
    q += scr[(size_t)i * 4096 + 2048 + f];
  }
  const float m = s * (1.0f / NNODES);
  mu[f] = m;
  inv[f] = rsqrtf(q * (1.0f / NNODES) - m * m + 1e-5f);
}

// normed (bf16) = BN(concat(x,hp)) * gamma + beta ; grid 4096 x 256
__global__ __launch_bounds__(256) void k_norm(const float* __restrict__ x,
                                              const float* __restrict__ hp,
                                              const float* __restrict__ mu,
                                              const float* __restrict__ inv,
                                              const float* __restrict__ gamma,
                                              const float* __restrict__ beta,
                                              short* __restrict__ nrm) {
  const int gid = blockIdx.x * 256 + threadIdx.x;
  const int n = gid >> 8, f = (gid & 255) << 2;
  float4 v = (f < 512) ? *(const float4*)(x + (size_t)n * 512 + f)
                       : *(const float4*)(hp + (size_t)n * 512 + (f - 512));
  short4v o;
  o[0] = f2bf((v.x - mu[f + 0]) * inv[f + 0] * gamma[f + 0] + beta[f + 0]);
  o[1] = f2bf((v.y - mu[f + 1]) * inv[f + 1] * gamma[f + 1] + beta[f + 1]);
  o[2] = f2bf((v.z - mu[f + 2]) * inv[f + 2] * gamma[f + 2] + beta[f + 2]);
  o[3] = f2bf((v.w - mu[f + 3]) * inv[f + 3] * gamma[f + 3] + beta[f + 3]);
  *(short4v*)(nrm + (size_t)n * 1024 + f) = o;
}

// ===========================================================================
extern "C" void kernel_launch(void* const* d_in, const int* in_sizes, int n_in,
                              void* d_out, int out_size, void* d_ws, size_t ws_size,
                              hipStream_t stream) {
  const float* x     = (const float*)d_in[0];
  const float* Bg    = (const float*)d_in[2];
  const int*   sidx  = (const int*)d_in[3];
  const int*   sind  = (const int*)d_in[4];
  const float* Wq    = (const float*)d_in[6];
  const float* bq    = (const float*)d_in[7];
  const float* Wk    = (const float*)d_in[8];
  const float* bk    = (const float*)d_in[9];
  const float* Wv    = (const float*)d_in[10];
  const float* bv    = (const float*)d_in[11];
  const float* Wo    = (const float*)d_in[12];
  const float* bo    = (const float*)d_in[13];
  const float* Wmp   = (const float*)d_in[14];
  const float* bmp   = (const float*)d_in[15];
  const float* gamma = (const float*)d_in[16];
  const float* beta  = (const float*)d_in[17];
  const float* Wex   = (const float*)d_in[18];
  const float* bex   = (const float*)d_in[19];
  const float* ssp   = (const float*)d_in[20];

  char* W = (char*)d_ws;
  short* x_bf  = (short*)(W + 0);          // 4 MiB
  short* WcatT = (short*)(W + 4194304);    // 2 MiB  [2048][512]
  short* WexT  = (short*)(W + 6291456);    // 1 MiB  [512][1024]
  short* WoT   = (short*)(W + 7340032);    // 512 KiB [512][512]
  float* bcat  = (float*)(W + 7864320);    // 8 KiB
  short* qT    = (short*)(W + 7872512);    // 4 MiB [32][1024][64]
  short* kT    = (short*)(W + 12066816);   // 4 MiB
  short* vT    = (short*)(W + 16261120);   // 4 MiB
  short* g_bf  = (short*)(W + 20455424);   // 4 MiB
  float* hp    = (float*)(W + 24649728);   // 8 MiB
  short* nrm   = (short*)(W + 33038336);   // 8 MiB [4096][1024]
  short* ex_bf = (short*)(W + 41426944);   // 4 MiB
  float* Ksc   = (float*)(W + 45621248);   // 16 MiB [4][1024][1024]
  short* o_bf  = (short*)(W + 62398464);   // 4 MiB
  float* scr   = (float*)(W + 66592768);   // 512 KiB
  float* muv   = (float*)(W + 67117056);   // 4 KiB
  float* invv  = (float*)(W + 67121152);   // 4 KiB

  float* outp = (float*)d_out;
  float* attn = outp + (size_t)BB * LL * HD;

  dim3 t256(256), t32x8(32, 8);

  // casts / packing
  k_cast_x<<<dim3(1024), t256, 0, stream>>>(x, x_bf);
  k_tcast5<<<dim3(16, 16, 5), t32x8, 0, stream>>>(Wq, Wk, Wv, Wmp, Wo, WcatT, WoT);
  k_tcast<<<dim3(16, 32), t32x8, 0, stream>>>(Wex, WexT, 1024, 512);
  k_pack_bias<<<dim3(8), t256, 0, stream>>>(bq, bk, bv, bmp, bcat);

  // fused QKV + message passing
  k_gemm_qkvg<<<dim3(16, 32), t256, 0, stream>>>(x_bf, WcatT, bcat, x, qT, kT, vT, g_bf);

  // extractor
  k_segmean<<<dim3(NNODES), dim3(128), 0, stream>>>(g_bf, sidx, sind, hp);
  k_stats1<<<dim3(32), t256, 0, stream>>>(x, hp, scr);
  k_stats2<<<dim3(8), dim3(128), 0, stream>>>(scr, muv, invv);
  k_norm<<<dim3(4096), t256, 0, stream>>>(x, hp, muv, invv, gamma, beta, nrm);
  k_gemm_ex<<<dim3(4, 64), t256, 0, stream>>>(nrm, WexT, bex, ex_bf);

  // structural bias (fused with B_graph + struct_scale)
  k_kstruct<<<dim3(8, 8, 4), t256, 0, stream>>>(ex_bf, Bg, ssp, Ksc);

  // fused attention (scores + softmax + PV)
  k_attn<<<dim3(16, 32), t256, 0, stream>>>(qT, kT, vT, Ksc, attn, o_bf);

  // output projection
  k_gemm_oproj<<<dim3(4, 64), t256, 0, stream>>>(o_bf, WoT, bo, outp);
}

// Round 9
// 395.728 us; speedup vs baseline: 1.0659x; 1.0659x over previous
//
#include <hip/hip_runtime.h>
#include <math.h>

// Problem constants
#define BB 4
#define LL 1024
#define DD 512
#define HH 8
#define DHH 64
#define EE 65536
#define NNODES 4096
#define HD 512
#define TWO_D 1024

typedef short bf16x8 __attribute__((ext_vector_type(8)));
typedef short short4v __attribute__((ext_vector_type(4)));
typedef float f32x4 __attribute__((ext_vector_type(4)));
typedef unsigned int u32;
#define GL_AS __attribute__((address_space(1)))
#define LDS_AS __attribute__((address_space(3)))

__device__ __forceinline__ short f2bf(float f) {   // RNE fp32->bf16
  u32 u = __builtin_bit_cast(u32, f);
  u = (u + 0x7fffu + ((u >> 16) & 1u)) >> 16;
  return (short)u;
}
__device__ __forceinline__ float b2f(short s) {
  u32 u = ((u32)(unsigned short)s) << 16;
  return __builtin_bit_cast(float, u);
}
__device__ __forceinline__ void gload_lds16(const short* g, short* l) {
  __builtin_amdgcn_global_load_lds((GL_AS const u32*)g, (LDS_AS u32*)l, 16, 0, 0);
}

// ---- stage ROWS x 32 bf16 tile (linear LDS, used by plain GEMMs)
template <int ROWS>
__device__ __forceinline__ void stage32(const short* g, int lda, short* lds, int tid) {
  const int w = tid >> 6, l = tid & 63;
#pragma unroll
  for (int rep = 0; rep < ROWS / 64; ++rep) {
    const int rbase = rep * 64 + w * 16;
    gload_lds16(g + (size_t)(rbase + (l >> 2)) * lda + (l & 3) * 8, lds + rbase * 32);
  }
}

// ---- one K=32 MFMA step from linear LDS tiles (BT layout both sides)
template <int MREP, int NREP>
__device__ __forceinline__ void mfma_step(const short* As, const short* Bs, int lds_ld, int kofs,
                                          f32x4 (&acc)[MREP][NREP], int wr, int wc, int l) {
  bf16x8 a[MREP], b[NREP];
#pragma unroll
  for (int mi = 0; mi < MREP; ++mi) {
    const int row = wr * (MREP * 16) + mi * 16 + (l & 15);
    a[mi] = *(const bf16x8*)(As + row * lds_ld + kofs + ((l >> 4) << 3));
  }
#pragma unroll
  for (int ni = 0; ni < NREP; ++ni) {
    const int row = wc * (NREP * 16) + ni * 16 + (l & 15);
    b[ni] = *(const bf16x8*)(Bs + row * lds_ld + kofs + ((l >> 4) << 3));
  }
#pragma unroll
  for (int mi = 0; mi < MREP; ++mi)
#pragma unroll
    for (int ni = 0; ni < NREP; ++ni)
      acc[mi][ni] = __builtin_amdgcn_mfma_f32_16x16x32_bf16(a[mi], b[ni], acc[mi][ni], 0, 0, 0);
}

// ---- swizzled LDS read: row-major tile, ROWB bytes per row, XOR bank swizzle
template <int ROWB>
__device__ __forceinline__ bf16x8 ldsw(const short* base, int row, int bir) {
  const int bo = (row * ROWB + bir) ^ ((row & 7) << 4);
  return *(const bf16x8*)((const char*)base + bo);
}

// ===========================================================================
// casts
// ===========================================================================
__global__ __launch_bounds__(256) void k_cast_x(const float* __restrict__ x, short* __restrict__ xb) {
  const int i = (blockIdx.x * 256 + threadIdx.x) * 8;
  float4 f0 = *(const float4*)(x + i), f1 = *(const float4*)(x + i + 4);
  bf16x8 s;
  s[0] = f2bf(f0.x); s[1] = f2bf(f0.y); s[2] = f2bf(f0.z); s[3] = f2bf(f0.w);
  s[4] = f2bf(f1.x); s[5] = f2bf(f1.y); s[6] = f2bf(f1.z); s[7] = f2bf(f1.w);
  *(bf16x8*)(xb + i) = s;
}

// 5 x [512][512] fp32 -> bf16 transposed; grid (16,16,5), block (32,8)
__global__ __launch_bounds__(256) void k_tcast5(const float* __restrict__ Wq, const float* __restrict__ Wk,
                                                const float* __restrict__ Wv, const float* __restrict__ Wmp,
                                                const float* __restrict__ Wo,
                                                short* __restrict__ WcatT, short* __restrict__ WoT) {
  __shared__ float t[32][33];
  const int zz = blockIdx.z;
  const float* W = (zz == 0) ? Wq : (zz == 1) ? Wk : (zz == 2) ? Wv : (zz == 3) ? Wmp : Wo;
  short* out = (zz < 4) ? (WcatT + zz * 512 * 512) : WoT;
  const int k0 = blockIdx.y * 32, n0 = blockIdx.x * 32;
  const int tx = threadIdx.x, ty = threadIdx.y;
#pragma unroll
  for (int i = 0; i < 4; ++i)
    t[ty + 8 * i][tx] = W[(size_t)(k0 + ty + 8 * i) * 512 + n0 + tx];
  __syncthreads();
#pragma unroll
  for (int i = 0; i < 4; ++i)
    out[(size_t)(n0 + ty + 8 * i) * 512 + k0 + tx] = f2bf(t[tx][ty + 8 * i]);
}

// W fp32 [K][N] -> out bf16 [N][K]; grid (N/32, K/32), block (32,8)
__global__ __launch_bounds__(256) void k_tcast(const float* __restrict__ W, short* __restrict__ out,
                                               int K, int N) {
  __shared__ float t[32][33];
  const int k0 = blockIdx.y * 32, n0 = blockIdx.x * 32;
  const int tx = threadIdx.x, ty = threadIdx.y;
#pragma unroll
  for (int i = 0; i < 4; ++i)
    t[ty + 8 * i][tx] = W[(size_t)(k0 + ty + 8 * i) * N + n0 + tx];
  __syncthreads();
#pragma unroll
  for (int i = 0; i < 4; ++i)
    out[(size_t)(n0 + ty + 8 * i) * K + k0 + tx] = f2bf(t[tx][ty + 8 * i]);
}

__global__ __launch_bounds__(256) void k_pack_bias(const float* bq, const float* bk,
                                                   const float* bv, const float* bmp,
                                                   float* __restrict__ bcat) {
  const int i = blockIdx.x * 256 + threadIdx.x;
  const float* src = (i < 512) ? bq : (i < 1024) ? bk : (i < 1536) ? bv : bmp;
  bcat[i] = src[i & 511];
}

// ===========================================================================
// V transpose: vT[z][j][dh] -> vTT[z][dh][j]; grid (16, 32)
// ===========================================================================
__global__ __launch_bounds__(256) void k_vtt(const short* __restrict__ vT, short* __restrict__ vTT) {
  __shared__ short t[64][65];
  const int z = blockIdx.y, j0 = blockIdx.x * 64;
  const short* src = vT + (size_t)z * 65536;
  short* dst = vTT + (size_t)z * 65536;
  const int tid = threadIdx.x;
  const int jr = tid >> 3, c0 = (tid & 7) * 8;
#pragma unroll
  for (int rep = 0; rep < 2; ++rep) {
    bf16x8 v = *(const bf16x8*)(src + (size_t)(j0 + jr + rep * 32) * 64 + c0);
#pragma unroll
    for (int i = 0; i < 8; ++i) t[jr + rep * 32][c0 + i] = v[i];
  }
  __syncthreads();
#pragma unroll
  for (int rep = 0; rep < 2; ++rep) {
    const int d = (tid >> 3) + rep * 32;
    bf16x8 o;
#pragma unroll
    for (int i = 0; i < 8; ++i) o[i] = t[c0 + i][d];
    *(bf16x8*)(dst + (size_t)d * 1024 + j0 + c0) = o;
  }
}

// ===========================================================================
// fused QKV + message-passing GEMM: [4096x512] @ [512x2048] (BT weights)
// ===========================================================================
__global__ __launch_bounds__(256) void k_gemm_qkvg(const short* __restrict__ A,
                                                   const short* __restrict__ Bw,
                                                   const float* __restrict__ bcat,
                                                   const float* __restrict__ x,
                                                   short* __restrict__ qT, short* __restrict__ kT,
                                                   short* __restrict__ vT, short* __restrict__ g_bf) {
  __shared__ __align__(16) short As[128 * 32];
  __shared__ __align__(16) short Bs[128 * 32];
  const int tid = threadIdx.x, l = tid & 63, w = tid >> 6, wr = w >> 1, wc = w & 1;
  const int m0 = blockIdx.y * 128, n0 = blockIdx.x * 128;
  f32x4 acc[4][4] = {};
  for (int k0 = 0; k0 < 512; k0 += 32) {
    stage32<128>(A + (size_t)m0 * 512 + k0, 512, As, tid);
    stage32<128>(Bw + (size_t)n0 * 512 + k0, 512, Bs, tid);
    __syncthreads();
    mfma_step<4, 4>(As, Bs, 32, 0, acc, wr, wc, l);
    __syncthreads();
  }
  const int lr = l >> 4, lc = l & 15;
#pragma unroll
  for (int mi = 0; mi < 4; ++mi)
#pragma unroll
    for (int ni = 0; ni < 4; ++ni) {
      const int col = n0 + wc * 64 + ni * 16 + lc;
      const int which = col >> 9;
#pragma unroll
      for (int r = 0; r < 4; ++r) {
        const int row = m0 + wr * 64 + mi * 16 + lr * 4 + r;
        float v = acc[mi][ni][r] + bcat[col];
        if (which < 3) {
          const int hh = (col >> 6) & 7, dh = col & 63;
          const int bb = row >> 10, ll2 = row & 1023;
          short* dst = (which == 0) ? qT : (which == 1) ? kT : vT;
          dst[((size_t)((bb * 8 + hh) * 1024 + ll2)) * 64 + dh] = f2bf(v);
        } else {
          const int c = col & 511;
          g_bf[(size_t)row * 512 + c] = f2bf(v + x[(size_t)row * 512 + c]);
        }
      }
    }
}

// ===========================================================================
// generic BT GEMM 64x128 tile: ex (K=1024) and out-proj (K=512)
// ===========================================================================
__global__ __launch_bounds__(256) void k_gemm_ex(const short* __restrict__ A,
                                                 const short* __restrict__ Bw,
                                                 const float* __restrict__ bias,
                                                 short* __restrict__ C) {
  __shared__ __align__(16) short As[64 * 32];
  __shared__ __align__(16) short Bs[128 * 32];
  const int tid = threadIdx.x, l = tid & 63, w = tid >> 6, wr = w >> 1, wc = w & 1;
  const int m0 = blockIdx.y * 64, n0 = blockIdx.x * 128;
  f32x4 acc[2][4] = {};
  for (int k0 = 0; k0 < 1024; k0 += 32) {
    stage32<64>(A + (size_t)m0 * 1024 + k0, 1024, As, tid);
    stage32<128>(Bw + (size_t)n0 * 1024 + k0, 1024, Bs, tid);
    __syncthreads();
    mfma_step<2, 4>(As, Bs, 32, 0, acc, wr, wc, l);
    __syncthreads();
  }
  const int lr = l >> 4, lc = l & 15;
#pragma unroll
  for (int mi = 0; mi < 2; ++mi)
#pragma unroll
    for (int ni = 0; ni < 4; ++ni) {
      const int col = n0 + wc * 64 + ni * 16 + lc;
      const float bv = bias[col];
#pragma unroll
      for (int r = 0; r < 4; ++r) {
        const int row = m0 + wr * 32 + mi * 16 + lr * 4 + r;
        C[(size_t)row * 512 + col] = f2bf(acc[mi][ni][r] + bv);
      }
    }
}

__global__ __launch_bounds__(256) void k_gemm_oproj(const short* __restrict__ A,
                                                    const short* __restrict__ Bw,
                                                    const float* __restrict__ bias,
                                                    float* __restrict__ C) {
  __shared__ __align__(16) short As[64 * 32];
  __shared__ __align__(16) short Bs[128 * 32];
  const int tid = threadIdx.x, l = tid & 63, w = tid >> 6, wr = w >> 1, wc = w & 1;
  const int m0 = blockIdx.y * 64, n0 = blockIdx.x * 128;
  f32x4 acc[2][4] = {};
  for (int k0 = 0; k0 < 512; k0 += 32) {
    stage32<64>(A + (size_t)m0 * 512 + k0, 512, As, tid);
    stage32<128>(Bw + (size_t)n0 * 512 + k0, 512, Bs, tid);
    __syncthreads();
    mfma_step<2, 4>(As, Bs, 32, 0, acc, wr, wc, l);
    __syncthreads();
  }
  const int lr = l >> 4, lc = l & 15;
#pragma unroll
  for (int mi = 0; mi < 2; ++mi)
#pragma unroll
    for (int ni = 0; ni < 4; ++ni) {
      const int col = n0 + wc * 64 + ni * 16 + lc;
      const float bv = bias[col];
#pragma unroll
      for (int r = 0; r < 4; ++r) {
        const int row = m0 + wr * 32 + mi * 16 + lr * 4 + r;
        C[(size_t)row * 512 + col] = acc[mi][ni][r] + bv;
      }
    }
}

// ===========================================================================
// K_struct combined bias, pre-scaled to log2 domain:
//   Ksc = (ss * (ex@ex^T)/sqrt(512) + Bg) * log2(e)     (causal tiles)
// Ksc feeds ONLY the attention exp path, so the log2e fold is exact.
// ===========================================================================
__global__ __launch_bounds__(256) void k_kstruct(const short* __restrict__ ex,
                                                 const float* __restrict__ Bg,
                                                 const float* __restrict__ ssp,
                                                 float* __restrict__ Ksc) {
  const int mt = blockIdx.y, nt = blockIdx.x, b = blockIdx.z;
  if (nt > mt) return;
  __shared__ __align__(16) short As[128 * 32];
  __shared__ __align__(16) short Bs[128 * 32];
  const int tid = threadIdx.x, l = tid & 63, w = tid >> 6, wr = w >> 1, wc = w & 1;
  const int m0 = mt * 128, n0 = nt * 128;
  const short* Az = ex + (size_t)b * 1024 * 512;
  f32x4 acc[4][4] = {};
  for (int k0 = 0; k0 < 512; k0 += 32) {
    stage32<128>(Az + (size_t)m0 * 512 + k0, 512, As, tid);
    stage32<128>(Az + (size_t)n0 * 512 + k0, 512, Bs, tid);
    __syncthreads();
    mfma_step<4, 4>(As, Bs, 32, 0, acc, wr, wc, l);
    __syncthreads();
  }
  const float l2e = 1.4426950408889634f;
  const float sc = ssp[0] * 0.04419417382415922f * l2e;  // ss/sqrt(512)*log2e
  const float* Bgb = Bg + (size_t)b * 1024 * 1024;
  float* Kb = Ksc + (size_t)b * 1024 * 1024;
  const int lr = l >> 4, lc = l & 15;
#pragma unroll
  for (int mi = 0; mi < 4; ++mi)
#pragma unroll
    for (int ni = 0; ni < 4; ++ni) {
      const int col = n0 + wc * 64 + ni * 16 + lc;
#pragma unroll
      for (int r = 0; r < 4; ++r) {
        const int row = m0 + wr * 64 + mi * 16 + lr * 4 + r;
        Kb[(size_t)row * 1024 + col] =
            fmaf(acc[mi][ni][r], sc, Bgb[(size_t)row * 1024 + col] * l2e);
      }
    }
}

// ===========================================================================
// Fused attention: scores + softmax + PV, two-pass flash style, log2 domain.
// grid (32, 32): bx -> mt (complement-remapped), by -> z.
// Block: 32 Q-rows, 64-col KV tiles, 4 waves (wr rows / wc col-halves).
// LDS 24.5 KB; 1024 blocks -> 4 blocks/CU, 50% occupancy cap.
// ===========================================================================
#define QSC 0.18033688011112042f  /* 0.125 * log2(e) */

__global__ __launch_bounds__(256) void k_attn(const short* __restrict__ qT,
                                              const short* __restrict__ kT,
                                              const short* __restrict__ vTT,
                                              const float* __restrict__ Ksc,
                                              float* __restrict__ attn,
                                              short* __restrict__ o_bf) {
  __shared__ __align__(16) short Qs[32 * 64];    // [qrow][k]  swizzled
  __shared__ __align__(16) short Ks[64 * 64];    // [kcol][k]  swizzled
  __shared__ __align__(16) short Ps[32 * 64];    // [qrow][j]  swizzled
  __shared__ __align__(16) short Vls[64 * 64];   // [dh][j]    swizzled
  __shared__ float mred[2][32], sred[2][32];

  const int tid = threadIdx.x, l = tid & 63, w = tid >> 6;
  const int wr = w >> 1, wc = w & 1, lr = l >> 4, lc = l & 15;
  const int z = blockIdx.y, b = z >> 3, h = z & 7;
  const int mt = (z & 16) ? (31 - (int)blockIdx.x) : (int)blockIdx.x;
  const int r0 = mt * 32;
  const int NT = (mt >> 1) + 1;   // 64-col tiles needed

  const short* Qz = qT + (size_t)z * 65536 + (size_t)r0 * 64;
  const short* Kz = kT + (size_t)z * 65536;
  const short* Vz = vTT + (size_t)z * 65536;
  const float* Kb = Ksc + (size_t)b * 1048576 + (size_t)r0 * 1024;
  float* Az = attn + (size_t)z * 1048576 + (size_t)r0 * 1024;

  // stage Q (32 rows; source pre-swizzled for XOR-bank layout)
  {
    const int rbase = w * 8;
    gload_lds16(Qz + (size_t)(rbase + (l >> 3)) * 64 + ((l & 7) ^ (l >> 3)) * 8,
                Qs + rbase * 64);
  }

  // zero-fill attn cols >= NT*64 for our 32 rows (d_out is poisoned)
  const int zc0 = NT * 64;
  if (zc0 < 1024) {
    const int cw = (1024 - zc0) >> 2;
    for (int idx = tid; idx < 32 * cw; idx += 256) {
      const int rowi = idx / cw, c4 = idx - rowi * cw;
      float4 zf = {0.f, 0.f, 0.f, 0.f};
      *(float4*)&Az[(size_t)rowi * 1024 + zc0 + (c4 << 2)] = zf;
    }
  }

  float m2[4], s2[4];
#pragma unroll
  for (int i = 0; i < 4; ++i) { m2[i] = -INFINITY; s2[i] = 0.f; }

  // ---------------- pass 1: per-row online max / sum (log2 domain) ----------
  for (int nt = 0; nt < NT; ++nt) {
    const int n0 = nt * 64;
    __syncthreads();
#pragma unroll
    for (int rep = 0; rep < 2; ++rep) {
      const int rbase = rep * 32 + w * 8;
      gload_lds16(Kz + (size_t)(n0 + rbase + (l >> 3)) * 64 + ((l & 7) ^ (l >> 3)) * 8,
                  Ks + rbase * 64);
    }
    __syncthreads();
    f32x4 acc[2] = {};
#pragma unroll
    for (int kk = 0; kk < 2; ++kk) {
      const int bir = kk * 64 + lr * 16;
      bf16x8 a = ldsw<128>(Qs, wr * 16 + lc, bir);
#pragma unroll
      for (int ni = 0; ni < 2; ++ni) {
        bf16x8 bb = ldsw<128>(Ks, wc * 32 + ni * 16 + lc, bir);
        acc[ni] = __builtin_amdgcn_mfma_f32_16x16x32_bf16(a, bb, acc[ni], 0, 0, 0);
      }
    }
#pragma unroll
    for (int rr = 0; rr < 4; ++rr) {
      const int rowl = wr * 16 + lr * 4 + rr;
      float vals[2], tm = -INFINITY;
#pragma unroll
      for (int ni = 0; ni < 2; ++ni) {
        const int coll = wc * 32 + ni * 16 + lc;
        float sc = fmaf(acc[ni][rr], QSC, Kb[(size_t)rowl * 1024 + n0 + coll]);
        if (n0 + coll > r0 + rowl) sc = -INFINITY;
        vals[ni] = sc;
        tm = fmaxf(tm, sc);
      }
      if (tm > -INFINITY) {
        const float mn = fmaxf(m2[rr], tm);
        s2[rr] = s2[rr] * exp2f(m2[rr] - mn) + exp2f(vals[0] - mn) + exp2f(vals[1] - mn);
        m2[rr] = mn;
      }
    }
  }

  // cross-lane combine (lanes sharing lr cover the 32 cols of this wc half)
#pragma unroll
  for (int off = 1; off < 16; off <<= 1)
#pragma unroll
    for (int i = 0; i < 4; ++i) {
      const float mo = __shfl_xor(m2[i], off, 64);
      const float so = __shfl_xor(s2[i], off, 64);
      const float mn = fmaxf(m2[i], mo);
      if (mn > -INFINITY)
        s2[i] = s2[i] * exp2f(m2[i] - mn) + so * exp2f(mo - mn);
      m2[i] = mn;
    }
  // cross-wave (wc halves) combine via LDS
  if (lc == 0) {
#pragma unroll
    for (int rr = 0; rr < 4; ++rr) {
      const int rowl = wr * 16 + lr * 4 + rr;
      mred[wc][rowl] = m2[rr];
      sred[wc][rowl] = s2[rr];
    }
  }
  __syncthreads();
  float mfv[4], invs[4];
#pragma unroll
  for (int rr = 0; rr < 4; ++rr) {
    const int rowl = wr * 16 + lr * 4 + rr;
    const float ma = mred[0][rowl], mb = mred[1][rowl];
    const float mF = fmaxf(ma, mb);
    const float sF = sred[0][rowl] * exp2f(ma - mF) + sred[1][rowl] * exp2f(mb - mF);
    mfv[rr] = mF;
    invs[rr] = 1.0f / sF;
  }

  // ---------------- pass 2: write P, accumulate O = P @ V -------------------
  f32x4 oacc[2] = {};
  for (int nt = 0; nt < NT; ++nt) {
    const int n0 = nt * 64;
    __syncthreads();
#pragma unroll
    for (int rep = 0; rep < 2; ++rep) {
      const int rbase = rep * 32 + w * 8;
      gload_lds16(Kz + (size_t)(n0 + rbase + (l >> 3)) * 64 + ((l & 7) ^ (l >> 3)) * 8,
                  Ks + rbase * 64);
      gload_lds16(Vz + (size_t)(rbase + (l >> 3)) * 1024 + n0 + ((l & 7) ^ (l >> 3)) * 8,
                  Vls + rbase * 64);
    }
    __syncthreads();
    f32x4 acc[2] = {};
#pragma unroll
    for (int kk = 0; kk < 2; ++kk) {
      const int bir = kk * 64 + lr * 16;
      bf16x8 a = ldsw<128>(Qs, wr * 16 + lc, bir);
#pragma unroll
      for (int ni = 0; ni < 2; ++ni) {
        bf16x8 bb = ldsw<128>(Ks, wc * 32 + ni * 16 + lc, bir);
        acc[ni] = __builtin_amdgcn_mfma_f32_16x16x32_bf16(a, bb, acc[ni], 0, 0, 0);
      }
    }
#pragma unroll
    for (int rr = 0; rr < 4; ++rr) {
      const int rowl = wr * 16 + lr * 4 + rr;
#pragma unroll
      for (int ni = 0; ni < 2; ++ni) {
        const int coll = wc * 32 + ni * 16 + lc;
        const float sc = fmaf(acc[ni][rr], QSC, Kb[(size_t)rowl * 1024 + n0 + coll]);
        float p = 0.f;
        if (n0 + coll <= r0 + rowl) p = exp2f(sc - mfv[rr]) * invs[rr];
        Az[(size_t)rowl * 1024 + n0 + coll] = p;
        *(short*)((char*)Ps + ((rowl * 128 + coll * 2) ^ ((rowl & 7) << 4))) = f2bf(p);
      }
    }
    __syncthreads();
    // PV: wave strip rows wr*16..+15, dh half wc*32..+31
#pragma unroll
    for (int kk = 0; kk < 2; ++kk) {
      const int bir = kk * 64 + lr * 16;
      bf16x8 a = ldsw<128>(Ps, wr * 16 + lc, bir);
#pragma unroll
      for (int ni = 0; ni < 2; ++ni) {
        bf16x8 bb = ldsw<128>(Vls, wc * 32 + ni * 16 + lc, bir);
        oacc[ni] = __builtin_amdgcn_mfma_f32_16x16x32_bf16(a, bb, oacc[ni], 0, 0, 0);
      }
    }
  }

  // O epilogue -> o_bf [b*1024+row][h*64+dh]
#pragma unroll
  for (int ni = 0; ni < 2; ++ni)
#pragma unroll
    for (int rr = 0; rr < 4; ++rr) {
      const int row = r0 + wr * 16 + lr * 4 + rr;
      const int dh = wc * 32 + ni * 16 + lc;
      o_bf[((size_t)(b * 1024 + row)) * 512 + h * 64 + dh] = f2bf(oacc[ni][rr]);
    }
}

// ===========================================================================
// segment mean over sorted indicator (g bf16 -> hp fp32)
// ===========================================================================
__global__ __launch_bounds__(128) void k_segmean(const short* __restrict__ g,
                                                 const int* __restrict__ idx,
                                                 const int* __restrict__ ind,
                                                 float* __restrict__ hp) {
  __shared__ int sh[2];
  const int s = blockIdx.x;
  if (threadIdx.x == 0) {
    int lo = 0, hi = EE;
    while (lo < hi) { int mid = (lo + hi) >> 1; if (ind[mid] < s) lo = mid + 1; else hi = mid; }
    sh[0] = lo;
    int lo2 = lo, hi2 = EE;
    while (lo2 < hi2) { int mid = (lo2 + hi2) >> 1; if (ind[mid] <= s) lo2 = mid + 1; else hi2 = mid; }
    sh[1] = lo2;
  }
  __syncthreads();
  const int lo = sh[0], hi = sh[1];
  const int d0 = threadIdx.x << 2;
  float a0 = 0.f, a1 = 0.f, a2 = 0.f, a3 = 0.f;
  for (int e = lo; e < hi; ++e) {
    const short4v v = *(const short4v*)(g + (size_t)idx[e] * 512 + d0);
    a0 += b2f(v[0]); a1 += b2f(v[1]); a2 += b2f(v[2]); a3 += b2f(v[3]);
  }
  const float ic = (hi > lo) ? 1.0f / (float)(hi - lo) : 0.0f;
  float4 o = {a0 * ic, a1 * ic, a2 * ic, a3 * ic};
  *(float4*)(hp + (size_t)s * 512 + d0) = o;
}

// ===========================================================================
// BN stats, row-major two-stage
// ===========================================================================
__global__ __launch_bounds__(256) void k_stats1(const float* __restrict__ x,
                                                const float* __restrict__ hp,
                                                float* __restrict__ scr) {
  const int blk = blockIdx.x, tid = threadIdx.x;
  const int c = tid * 2, r0 = blk * 128;
  float sx0 = 0, sx1 = 0, qx0 = 0, qx1 = 0, sh0 = 0, sh1 = 0, qh0 = 0, qh1 = 0;
  for (int r = 0; r < 128; ++r) {
    const size_t off = (size_t)(r0 + r) * 512 + c;
    float2 vx = *(const float2*)(x + off);
    float2 vh = *(const float2*)(hp + off);
    sx0 += vx.x; sx1 += vx.y; qx0 = fmaf(vx.x, vx.x, qx0); qx1 = fmaf(vx.y, vx.y, qx1);
    sh0 += vh.x; sh1 += vh.y; qh0 = fmaf(vh.x, vh.x, qh0); qh1 = fmaf(vh.y, vh.y, qh1);
  }
  float* p = scr + (size_t)blk * 4096;
  p[c] = sx0; p[c + 1] = sx1;
  p[512 + c] = sh0; p[512 + c + 1] = sh1;
  p[2048 + c] = qx0; p[2048 + c + 1] = qx1;
  p[2048 + 512 + c] = qh0; p[2048 + 512 + c + 1] = qh1;
}
__global__ __launch_bounds__(128) void k_stats2(const float* __restrict__ scr,
                                                float* __restrict__ mu, float* __restrict__ inv) {
  const int f = blockIdx.x * 128 + threadIdx.x;
  float s = 0.f, q = 0.f;
  for (int i = 0; i < 32; ++i) {
    s += scr[(size_t)i * 4096 + f];
    q += scr[(size_t)i * 4096 + 2048 + f];
  }
  const float m = s * (1.0f / NNODES);
  mu[f] = m;
  inv[f] = rsqrtf(q * (1.0f / NNODES) - m * m + 1e-5f);
}

// normed (bf16) = BN(concat(x,hp)) * gamma + beta ; grid 4096 x 256
__global__ __launch_bounds__(256) void k_norm(const float* __restrict__ x,
                                              const float* __restrict__ hp,
                                              const float* __restrict__ mu,
                                              const float* __restrict__ inv,
                                              const float* __restrict__ gamma,
                                              const float* __restrict__ beta,
                                              short* __restrict__ nrm) {
  const int gid = blockIdx.x * 256 + threadIdx.x;
  const int n = gid >> 8, f = (gid & 255) << 2;
  float4 v = (f < 512) ? *(const float4*)(x + (size_t)n * 512 + f)
                       : *(const float4*)(hp + (size_t)n * 512 + (f - 512));
  short4v o;
  o[0] = f2bf((v.x - mu[f + 0]) * inv[f + 0] * gamma[f + 0] + beta[f + 0]);
  o[1] = f2bf((v.y - mu[f + 1]) * inv[f + 1] * gamma[f + 1] + beta[f + 1]);
  o[2] = f2bf((v.z - mu[f + 2]) * inv[f + 2] * gamma[f + 2] + beta[f + 2]);
  o[3] = f2bf((v.w - mu[f + 3]) * inv[f + 3] * gamma[f + 3] + beta[f + 3]);
  *(short4v*)(nrm + (size_t)n * 1024 + f) = o;
}

// ===========================================================================
extern "C" void kernel_launch(void* const* d_in, const int* in_sizes, int n_in,
                              void* d_out, int out_size, void* d_ws, size_t ws_size,
                              hipStream_t stream) {
  const float* x     = (const float*)d_in[0];
  const float* Bg    = (const float*)d_in[2];
  const int*   sidx  = (const int*)d_in[3];
  const int*   sind  = (const int*)d_in[4];
  const float* Wq    = (const float*)d_in[6];
  const float* bq    = (const float*)d_in[7];
  const float* Wk    = (const float*)d_in[8];
  const float* bk    = (const float*)d_in[9];
  const float* Wv    = (const float*)d_in[10];
  const float* bv    = (const float*)d_in[11];
  const float* Wo    = (const float*)d_in[12];
  const float* bo    = (const float*)d_in[13];
  const float* Wmp   = (const float*)d_in[14];
  const float* bmp   = (const float*)d_in[15];
  const float* gamma = (const float*)d_in[16];
  const float* beta  = (const float*)d_in[17];
  const float* Wex   = (const float*)d_in[18];
  const float* bex   = (const float*)d_in[19];
  const float* ssp   = (const float*)d_in[20];

  char* W = (char*)d_ws;
  short* x_bf  = (short*)(W + 0);          // 4 MiB
  short* WcatT = (short*)(W + 4194304);    // 2 MiB  [2048][512]
  short* WexT  = (short*)(W + 6291456);    // 1 MiB  [512][1024]
  short* WoT   = (short*)(W + 7340032);    // 512 KiB [512][512]
  float* bcat  = (float*)(W + 7864320);    // 8 KiB
  short* qT    = (short*)(W + 7872512);    // 4 MiB [32][1024][64]
  short* kT    = (short*)(W + 12066816);   // 4 MiB
  short* vT    = (short*)(W + 16261120);   // 4 MiB
  short* g_bf  = (short*)(W + 20455424);   // 4 MiB
  float* hp    = (float*)(W + 24649728);   // 8 MiB
  short* nrm   = (short*)(W + 33038336);   // 8 MiB [4096][1024]
  short* ex_bf = (short*)(W + 41426944);   // 4 MiB
  float* Ksc   = (float*)(W + 45621248);   // 16 MiB [4][1024][1024]
  short* o_bf  = (short*)(W + 62398464);   // 4 MiB
  float* scr   = (float*)(W + 66592768);   // 512 KiB
  float* muv   = (float*)(W + 67117056);   // 4 KiB
  float* invv  = (float*)(W + 67121152);   // 4 KiB
  short* vTT   = (short*)(W + 67125248);   // 4 MiB [32][64][1024]

  float* outp = (float*)d_out;
  float* attn = outp + (size_t)BB * LL * HD;

  dim3 t256(256), t32x8(32, 8);

  // casts / packing
  k_cast_x<<<dim3(1024), t256, 0, stream>>>(x, x_bf);
  k_tcast5<<<dim3(16, 16, 5), t32x8, 0, stream>>>(Wq, Wk, Wv, Wmp, Wo, WcatT, WoT);
  k_tcast<<<dim3(16, 32), t32x8, 0, stream>>>(Wex, WexT, 1024, 512);
  k_pack_bias<<<dim3(8), t256, 0, stream>>>(bq, bk, bv, bmp, bcat);

  // fused QKV + message passing
  k_gemm_qkvg<<<dim3(16, 32), t256, 0, stream>>>(x_bf, WcatT, bcat, x, qT, kT, vT, g_bf);
  k_vtt<<<dim3(16, 32), t256, 0, stream>>>(vT, vTT);

  // extractor
  k_segmean<<<dim3(NNODES), dim3(128), 0, stream>>>(g_bf, sidx, sind, hp);
  k_stats1<<<dim3(32), t256, 0, stream>>>(x, hp, scr);
  k_stats2<<<dim3(8), dim3(128), 0, stream>>>(scr, muv, invv);
  k_norm<<<dim3(4096), t256, 0, stream>>>(x, hp, muv, invv, gamma, beta, nrm);
  k_gemm_ex<<<dim3(4, 64), t256, 0, stream>>>(nrm, WexT, bex, ex_bf);

  // structural bias (fused with B_graph + struct_scale, log2e pre-scaled)
  k_kstruct<<<dim3(8, 8, 4), t256, 0, stream>>>(ex_bf, Bg, ssp, Ksc);

  // fused attention (scores + softmax + PV)
  k_attn<<<dim3(32, 32), t256, 0, stream>>>(qT, kT, vTT, Ksc, attn, o_bf);

  // output projection
  k_gemm_oproj<<<dim3(4, 64), t256, 0, stream>>>(o_bf, WoT, bo, outp);
}